// Round 11
// baseline (351.383 us; speedup 1.0000x reference)
//
#include <hip/hip_runtime.h>
#include <math.h>

#define BB 2
#define LL 1024
#define DD 512
#define DIN 1024      // d_inner
#define NS 16         // d_state
#define RNK 32        // dt_rank
#define ML (BB*LL)    // 2048 rows
#define CT 16         // scan chunk length
#define NC (LL/CT)    // 64 chunks
#define BDIN (BB*DIN) // 2048

typedef unsigned short u16;
typedef unsigned int u32;

__device__ __forceinline__ float sigmoidf_(float v) { return 1.f / (1.f + __expf(-v)); }
__device__ __forceinline__ float siluf_(float v) { return v * sigmoidf_(v); }
__device__ __forceinline__ u16 f2bf(float f) {
  union { float f; u32 u; } c; c.f = f;
  u32 r = c.u + 0x7fffu + ((c.u >> 16) & 1u);
  return (u16)(r >> 16);
}
__device__ __forceinline__ float bf2f(u16 x) {
  union { u32 u; float f; } c; c.u = (u32)x << 16;
  return c.f;
}

// ---------------- fused bf16 cast of x + all weights (one launch) ----------------
// 2048 elems/block: x 512 | W_in 512 | W_xp 32 | W_dt 16 | W_out 256 | W_ff1 256 | W_ff2 256
__global__ __launch_bounds__(256) void cast_all(const float* __restrict__ x,
                                                const float* __restrict__ Wi,
                                                const float* __restrict__ Wx,
                                                const float* __restrict__ Wd,
                                                const float* __restrict__ Wo,
                                                const float* __restrict__ Wf1,
                                                const float* __restrict__ Wf2,
                                                u16* bx, u16* bWi, u16* bWx, u16* bWd,
                                                u16* bWo, u16* bWf1, u16* bWf2)
{
  int bid = blockIdx.x;
  const float* src; u16* dst; int base;
  if (bid < 512)       { src = x;   dst = bx;   base = 0; }
  else if (bid < 1024) { src = Wi;  dst = bWi;  base = 512; }
  else if (bid < 1056) { src = Wx;  dst = bWx;  base = 1024; }
  else if (bid < 1072) { src = Wd;  dst = bWd;  base = 1056; }
  else if (bid < 1328) { src = Wo;  dst = bWo;  base = 1072; }
  else if (bid < 1584) { src = Wf1; dst = bWf1; base = 1328; }
  else                 { src = Wf2; dst = bWf2; base = 1584; }
  int i = ((bid - base) * 256 + threadIdx.x) * 8;
  float4 v0 = *(const float4*)&src[i];
  float4 v1 = *(const float4*)&src[i + 4];
  union { u16 u[8]; uint4 v; } p;
  p.u[0] = f2bf(v0.x); p.u[1] = f2bf(v0.y); p.u[2] = f2bf(v0.z); p.u[3] = f2bf(v0.w);
  p.u[4] = f2bf(v1.x); p.u[5] = f2bf(v1.y); p.u[6] = f2bf(v1.z); p.u[7] = f2bf(v1.w);
  *(uint4*)&dst[i] = p.v;
}

// ---------------- tiled bf16 MFMA GEMM: C[M,N] = A[M,K] @ W[N,K]^T ----------------
// EPI: 0 none, 1 +bias, 2 +bias+gelu, 3 +bias+softplus.  OT: float or u16
using bf16x8 = __attribute__((ext_vector_type(8))) short;
using f32x4  = __attribute__((ext_vector_type(4))) float;

template<int BM, int BN, int EPI, typename OT>
__global__ __launch_bounds__(256) void gemm_t(const u16* __restrict__ A,
                                              const u16* __restrict__ W,
                                              const float* __restrict__ bias,
                                              OT* __restrict__ C,
                                              int M, int N, int K)
{
  constexpr int WR = BM / 64;
  constexpr int WC = 4 / WR;
  constexpr int NW = BN / WC;       // cols per wave
  constexpr int JJ = NW / 16;       // 16-col fragments per wave
  constexpr int RB = BN / 64;       // B row-groups for staging
  __shared__ u16 As[BM][40];        // pad to 40: 2-way bank alias = free
  __shared__ u16 Bs[BN][40];
  const int bm = blockIdx.y * BM, bn = blockIdx.x * BN;
  const int tid = threadIdx.x;
  const int w = tid >> 6, l = tid & 63;
  const int wr = w / WC, wc = w % WC;
  const int lr = l & 15, lh = l >> 4;
  const int sr0 = tid >> 2, sc0 = tid & 3;
  f32x4 acc[4][JJ] = {};
  for (int k0 = 0; k0 < K; k0 += 32) {
    uint4 areg[WR], breg[RB];
#pragma unroll
    for (int i = 0; i < WR; ++i)
      areg[i] = *(const uint4*)&A[(size_t)(bm + sr0 + 64 * i) * K + k0 + sc0 * 8];
#pragma unroll
    for (int i = 0; i < RB; ++i)
      breg[i] = *(const uint4*)&W[(size_t)(bn + sr0 + 64 * i) * K + k0 + sc0 * 8];
    __syncthreads();
#pragma unroll
    for (int i = 0; i < WR; ++i) *(uint4*)&As[sr0 + 64 * i][sc0 * 8] = areg[i];
#pragma unroll
    for (int i = 0; i < RB; ++i) *(uint4*)&Bs[sr0 + 64 * i][sc0 * 8] = breg[i];
    __syncthreads();
    bf16x8 af[4], bfr[JJ];
#pragma unroll
    for (int i = 0; i < 4; ++i) af[i]  = *(bf16x8*)&As[wr * 64 + i * 16 + lr][lh * 8];
#pragma unroll
    for (int j = 0; j < JJ; ++j) bfr[j] = *(bf16x8*)&Bs[wc * NW + j * 16 + lr][lh * 8];
#pragma unroll
    for (int i = 0; i < 4; ++i)
#pragma unroll
      for (int j = 0; j < JJ; ++j)
        acc[i][j] = __builtin_amdgcn_mfma_f32_16x16x32_bf16(af[i], bfr[j], acc[i][j], 0, 0, 0);
  }
#pragma unroll
  for (int i = 0; i < 4; ++i) {
#pragma unroll
    for (int j = 0; j < JJ; ++j) {
      int col = bn + wc * NW + j * 16 + lr;
      float bv = (EPI >= 1) ? bias[col] : 0.f;
#pragma unroll
      for (int r = 0; r < 4; ++r) {
        int row = bm + wr * 64 + i * 16 + lh * 4 + r;
        float t = acc[i][j][r] + bv;
        if (EPI == 2) t = 0.5f * t * (1.f + erff(t * 0.70710678118654752f));
        if (EPI == 3) t = fmaxf(t, 0.f) + log1pf(__expf(-fabsf(t)));
        if constexpr (sizeof(OT) == 2) C[(size_t)row * N + col] = (OT)f2bf(t);
        else                           C[(size_t)row * N + col] = (OT)t;
      }
    }
  }
}

// ======== GEMM + row-LayerNorm fused (BM=64, BN=N=512, K=1024; 32 blocks) ========
// MODE 0 (out_proj+LN1): m=acc; v=x-m; LN(g,b) -> rb fp32 + brb bf16
// MODE 1 (ff2+final):    ff=acc+bias; v=silu(rln-ff); LN(g,b)+x -> out fp32
template<int MODE>
__global__ __launch_bounds__(256) void gemm_ln(const u16* __restrict__ A,
                                               const u16* __restrict__ W,
                                               const float* __restrict__ bias,
                                               const float* __restrict__ xres,
                                               const float* __restrict__ rln,
                                               const float* __restrict__ g,
                                               const float* __restrict__ b,
                                               float* __restrict__ outF,
                                               u16* __restrict__ outB)
{
  constexpr int K = DIN;   // 1024
  __shared__ u16 As[64][40];
  __shared__ u16 Bs[512][40];
  __shared__ float red[64][8];    // [row][wave*2 + {s,ss}]
  const int bm = blockIdx.x * 64;
  const int tid = threadIdx.x;
  const int wv = tid >> 6, l = tid & 63;
  const int lr = l & 15, lh = l >> 4;
  const int sr0 = tid >> 2, sc0 = tid & 3;
  f32x4 acc[4][8] = {};
  for (int k0 = 0; k0 < K; k0 += 32) {
    uint4 areg = *(const uint4*)&A[(size_t)(bm + sr0) * K + k0 + sc0 * 8];
    uint4 breg[8];
#pragma unroll
    for (int i = 0; i < 8; ++i)
      breg[i] = *(const uint4*)&W[(size_t)(sr0 + 64 * i) * K + k0 + sc0 * 8];
    __syncthreads();
    *(uint4*)&As[sr0][sc0 * 8] = areg;
#pragma unroll
    for (int i = 0; i < 8; ++i) *(uint4*)&Bs[sr0 + 64 * i][sc0 * 8] = breg[i];
    __syncthreads();
    bf16x8 af[4], bfr[8];
#pragma unroll
    for (int i = 0; i < 4; ++i) af[i]  = *(bf16x8*)&As[i * 16 + lr][lh * 8];
#pragma unroll
    for (int j = 0; j < 8; ++j) bfr[j] = *(bf16x8*)&Bs[wv * 128 + j * 16 + lr][lh * 8];
#pragma unroll
    for (int i = 0; i < 4; ++i)
#pragma unroll
      for (int j = 0; j < 8; ++j)
        acc[i][j] = __builtin_amdgcn_mfma_f32_16x16x32_bf16(af[i], bfr[j], acc[i][j], 0, 0, 0);
  }
  // ---- v-pass: overwrite acc with the pre-LN value ----
#pragma unroll
  for (int i = 0; i < 4; ++i)
#pragma unroll
    for (int j = 0; j < 8; ++j) {
      int col = wv * 128 + j * 16 + lr;
#pragma unroll
      for (int r = 0; r < 4; ++r) {
        int row = bm + i * 16 + lh * 4 + r;
        float a = acc[i][j][r];
        float v;
        if (MODE == 0) {
          v = xres[(size_t)row * DD + col] - a;
        } else {
          float ff = a + bias[col];
          v = siluf_(rln[(size_t)row * DD + col] - ff);
        }
        acc[i][j][r] = v;
      }
    }
  // ---- per-row partial sums over this wave's 128 cols ----
#pragma unroll
  for (int i = 0; i < 4; ++i)
#pragma unroll
    for (int r = 0; r < 4; ++r) {
      float s = 0.f, ss = 0.f;
#pragma unroll
      for (int j = 0; j < 8; ++j) {
        float v = acc[i][j][r];
        s += v; ss += v * v;
      }
      s  += __shfl_xor(s, 1, 16);  ss += __shfl_xor(ss, 1, 16);
      s  += __shfl_xor(s, 2, 16);  ss += __shfl_xor(ss, 2, 16);
      s  += __shfl_xor(s, 4, 16);  ss += __shfl_xor(ss, 4, 16);
      s  += __shfl_xor(s, 8, 16);  ss += __shfl_xor(ss, 8, 16);
      if (lr == 0) { red[i * 16 + lh * 4 + r][wv * 2] = s; red[i * 16 + lh * 4 + r][wv * 2 + 1] = ss; }
    }
  __syncthreads();
  // ---- normalize + write ----
#pragma unroll
  for (int i = 0; i < 4; ++i)
#pragma unroll
    for (int r = 0; r < 4; ++r) {
      int rlcl = i * 16 + lh * 4 + r;
      int row = bm + rlcl;
      float S  = red[rlcl][0] + red[rlcl][2] + red[rlcl][4] + red[rlcl][6];
      float SS = red[rlcl][1] + red[rlcl][3] + red[rlcl][5] + red[rlcl][7];
      float mean = S * (1.f / DD);
      float var = SS * (1.f / DD) - mean * mean;
      float rstd = rsqrtf(var + 1e-5f);
#pragma unroll
      for (int j = 0; j < 8; ++j) {
        int col = wv * 128 + j * 16 + lr;
        float vn = (acc[i][j][r] - mean) * rstd * g[col] + b[col];
        if (MODE == 0) {
          outF[(size_t)row * DD + col] = vn;
          outB[(size_t)row * DD + col] = f2bf(vn);
        } else {
          outF[(size_t)row * DD + col] = vn + xres[(size_t)row * DD + col];
        }
      }
    }
}

// ---------------- x_proj via MFMA: xdbl[M,64] = ucb @ Wxb^T (+ bf16 dt_r copy) ----------------
__global__ __launch_bounds__(256) void xproj_mfma(const u16* __restrict__ A,
                                                  const u16* __restrict__ W,
                                                  float* __restrict__ C,
                                                  u16* __restrict__ bdtr)
{
  __shared__ u16 As[128][40];
  __shared__ u16 Bs[64][40];
  const int bm = blockIdx.x * 128;
  const int tid = threadIdx.x;
  const int w = tid >> 6, l = tid & 63;
  const int lr = l & 15, lh = l >> 4;
  const int sr0 = tid >> 2, sc0 = tid & 3;
  f32x4 acc[2][4] = {};
  for (int k0 = 0; k0 < DIN; k0 += 32) {
    uint4 a0 = *(const uint4*)&A[(size_t)(bm + sr0) * DIN + k0 + sc0 * 8];
    uint4 a1 = *(const uint4*)&A[(size_t)(bm + sr0 + 64) * DIN + k0 + sc0 * 8];
    uint4 b0;
    if (sr0 < 64) b0 = *(const uint4*)&W[(size_t)sr0 * DIN + k0 + sc0 * 8];
    __syncthreads();
    *(uint4*)&As[sr0][sc0 * 8] = a0;
    *(uint4*)&As[sr0 + 64][sc0 * 8] = a1;
    if (sr0 < 64) *(uint4*)&Bs[sr0][sc0 * 8] = b0;
    __syncthreads();
    bf16x8 af[2], bfr[4];
#pragma unroll
    for (int i = 0; i < 2; ++i) af[i]  = *(bf16x8*)&As[w * 32 + i * 16 + lr][lh * 8];
#pragma unroll
    for (int j = 0; j < 4; ++j) bfr[j] = *(bf16x8*)&Bs[j * 16 + lr][lh * 8];
#pragma unroll
    for (int i = 0; i < 2; ++i)
#pragma unroll
      for (int j = 0; j < 4; ++j)
        acc[i][j] = __builtin_amdgcn_mfma_f32_16x16x32_bf16(af[i], bfr[j], acc[i][j], 0, 0, 0);
  }
#pragma unroll
  for (int i = 0; i < 2; ++i)
#pragma unroll
    for (int j = 0; j < 4; ++j) {
      int col = j * 16 + lr;
#pragma unroll
      for (int r = 0; r < 4; ++r) {
        int row = bm + w * 32 + i * 16 + lh * 4 + r;
        float v = acc[i][j][r];
        C[(size_t)row * 64 + col] = v;
        if (j < 2) bdtr[(size_t)row * RNK + col] = f2bf(v);   // dt_r cols 0..31
      }
    }
}

// ---------------- depthwise causal conv (K=4) + SiLU; bf16 in (xzb), bf16 out ----------------
__global__ __launch_bounds__(256) void conv_silu(const u16* __restrict__ xzb,
                                                 const float* __restrict__ conv_w,
                                                 const float* __restrict__ conv_b,
                                                 u16* __restrict__ ucb)
{
  int idx = blockIdx.x * 256 + threadIdx.x;
  int d = idx & (DIN - 1);
  int bl = idx >> 10;
  int l = bl & (LL - 1);
  int b = bl >> 10;
  float acc = conv_b[d];
#pragma unroll
  for (int k = 0; k < 4; ++k) {
    int ls = l - 3 + k;
    float uv = (ls >= 0) ? bf2f(xzb[((size_t)(b * LL + ls)) * (2 * DIN) + d]) : 0.f;
    acc = fmaf(uv, conv_w[d * 4 + k], acc);
  }
  ucb[idx] = f2bf(siluf_(acc));
}

// ================= chunked selective scan, register-state (3 kernels) =================
// thread = one d, 16 n-states in VGPRs. state layout: [c][n][b*DIN+d]. dt is bf16.

__global__ __launch_bounds__(256) void scan_p1(const u16* __restrict__ dtb,
                                               const u16* __restrict__ ucb,
                                               const float* __restrict__ xdbl,
                                               const float* __restrict__ A_log,
                                               float* __restrict__ apG,
                                               float* __restrict__ hG)
{
  __shared__ float dts[CT][256];
  __shared__ float us[CT][256];
  __shared__ float Bs[CT][NS];
  const int d0 = blockIdx.x * 256, c = blockIdx.y, b = blockIdx.z;
  const int tid = threadIdx.x;
  const int t0 = c * CT;
  for (int i = tid; i < CT * 64; i += 256) {
    int r = i >> 6, col = (i & 63) * 4;
    size_t row = (size_t)(b * LL + t0 + r);
    ushort4 dv = *(const ushort4*)&dtb[row * DIN + d0 + col];
    float4 df = { bf2f(dv.x), bf2f(dv.y), bf2f(dv.z), bf2f(dv.w) };
    *(float4*)&dts[r][col] = df;
    ushort4 uv = *(const ushort4*)&ucb[row * DIN + d0 + col];
    float4 uf = { bf2f(uv.x), bf2f(uv.y), bf2f(uv.z), bf2f(uv.w) };
    *(float4*)&us[r][col] = uf;
  }
  { int r = tid >> 4, n = tid & 15;
    Bs[r][n] = xdbl[(size_t)(b * LL + t0 + r) * 64 + 32 + n]; }
  __syncthreads();
  const int d = d0 + tid;
  float Ad[NS];
#pragma unroll
  for (int n = 0; n < NS; ++n) Ad[n] = -__expf(A_log[d * NS + n]);
  float h[NS] = {};
  float sdt = 0.f;
#pragma unroll 4
  for (int t = 0; t < CT; ++t) {
    float dtv = dts[t][tid];
    float dtu = dtv * us[t][tid];
    sdt += dtv;
    float4 B0 = *(float4*)&Bs[t][0],  B1 = *(float4*)&Bs[t][4];
    float4 B2 = *(float4*)&Bs[t][8],  B3 = *(float4*)&Bs[t][12];
    float Bq[NS] = { B0.x, B0.y, B0.z, B0.w, B1.x, B1.y, B1.z, B1.w,
                     B2.x, B2.y, B2.z, B2.w, B3.x, B3.y, B3.z, B3.w };
#pragma unroll
    for (int n = 0; n < NS; ++n) {
      float a = __expf(dtv * Ad[n]);
      h[n] = fmaf(a, h[n], dtu * Bq[n]);
    }
  }
  const int bd = b * DIN + d;
#pragma unroll
  for (int n = 0; n < NS; ++n) {
    apG[((size_t)c * NS + n) * BDIN + bd] = __expf(Ad[n] * sdt);
    hG [((size_t)c * NS + n) * BDIN + bd] = h[n];
  }
}

__global__ __launch_bounds__(128) void scan_p2(const float* __restrict__ apG,
                                               float* __restrict__ hG)
{
  const int idx = blockIdx.x * 128 + threadIdx.x;
  float H = 0.f;
#pragma unroll 16
  for (int c = 0; c < NC; ++c) {
    size_t o = (size_t)c * (NS * BDIN) + idx;
    float ap = apG[o];
    float hl = hG[o];
    hG[o] = H;
    H = fmaf(ap, H, hl);
  }
}

__global__ __launch_bounds__(256) void scan_p3(const u16* __restrict__ dtb,
                                               const u16* __restrict__ ucb,
                                               const u16* __restrict__ xzb,
                                               const float* __restrict__ xdbl,
                                               const float* __restrict__ A_log,
                                               const float* __restrict__ D_skip,
                                               const float* __restrict__ hG,
                                               u16* __restrict__ ygb)
{
  __shared__ float dts[CT][256];
  __shared__ float us[CT][256];
  __shared__ float zs[CT][256];
  __shared__ float Bs[CT][NS];
  __shared__ float Cs[CT][NS];
  const int d0 = blockIdx.x * 256, c = blockIdx.y, b = blockIdx.z;
  const int tid = threadIdx.x;
  const int t0 = c * CT;
  for (int i = tid; i < CT * 64; i += 256) {
    int r = i >> 6, col = (i & 63) * 4;
    size_t row = (size_t)(b * LL + t0 + r);
    ushort4 dv = *(const ushort4*)&dtb[row * DIN + d0 + col];
    float4 df = { bf2f(dv.x), bf2f(dv.y), bf2f(dv.z), bf2f(dv.w) };
    *(float4*)&dts[r][col] = df;
    ushort4 uv = *(const ushort4*)&ucb[row * DIN + d0 + col];
    float4 uf = { bf2f(uv.x), bf2f(uv.y), bf2f(uv.z), bf2f(uv.w) };
    *(float4*)&us[r][col] = uf;
    ushort4 zv = *(const ushort4*)&xzb[row * (2 * DIN) + DIN + d0 + col];
    float4 zf = { bf2f(zv.x), bf2f(zv.y), bf2f(zv.z), bf2f(zv.w) };
    *(float4*)&zs[r][col] = zf;
  }
  { int r = tid >> 4, n = tid & 15;
    size_t row = (size_t)(b * LL + t0 + r);
    Bs[r][n] = xdbl[row * 64 + 32 + n];
    Cs[r][n] = xdbl[row * 64 + 48 + n]; }
  __syncthreads();
  const int d = d0 + tid;
  const int bd = b * DIN + d;
  float Ad[NS];
#pragma unroll
  for (int n = 0; n < NS; ++n) Ad[n] = -__expf(A_log[d * NS + n]);
  const float Dd = D_skip[d];
  float h[NS];
#pragma unroll
  for (int n = 0; n < NS; ++n) h[n] = hG[((size_t)c * NS + n) * BDIN + bd];
#pragma unroll 2
  for (int t = 0; t < CT; ++t) {
    float dtv = dts[t][tid];
    float ucv = us[t][tid];
    float dtu = dtv * ucv;
    float4 B0 = *(float4*)&Bs[t][0],  B1 = *(float4*)&Bs[t][4];
    float4 B2 = *(float4*)&Bs[t][8],  B3 = *(float4*)&Bs[t][12];
    float4 C0 = *(float4*)&Cs[t][0],  C1 = *(float4*)&Cs[t][4];
    float4 C2 = *(float4*)&Cs[t][8],  C3 = *(float4*)&Cs[t][12];
    float Bq[NS] = { B0.x, B0.y, B0.z, B0.w, B1.x, B1.y, B1.z, B1.w,
                     B2.x, B2.y, B2.z, B2.w, B3.x, B3.y, B3.z, B3.w };
    float Cq[NS] = { C0.x, C0.y, C0.z, C0.w, C1.x, C1.y, C1.z, C1.w,
                     C2.x, C2.y, C2.z, C2.w, C3.x, C3.y, C3.z, C3.w };
    float y = 0.f;
#pragma unroll
    for (int n = 0; n < NS; ++n) {
      float a = __expf(dtv * Ad[n]);
      h[n] = fmaf(a, h[n], dtu * Bq[n]);
      y = fmaf(h[n], Cq[n], y);
    }
    float o = fmaf(ucv, Dd, y) * siluf_(zs[t][tid]);
    ygb[(size_t)(b * LL + t0 + t) * DIN + d0 + tid] = f2bf(o);
  }
}

extern "C" void kernel_launch(void* const* d_in, const int* in_sizes, int n_in,
                              void* d_out, int out_size, void* d_ws, size_t ws_size,
                              hipStream_t stream)
{
  const float* x      = (const float*)d_in[0];
  const float* W_in   = (const float*)d_in[1];
  const float* conv_w = (const float*)d_in[2];
  const float* conv_b = (const float*)d_in[3];
  const float* W_xp   = (const float*)d_in[4];
  const float* W_dt   = (const float*)d_in[5];
  const float* b_dt   = (const float*)d_in[6];
  const float* A_log  = (const float*)d_in[7];
  const float* D_skip = (const float*)d_in[8];
  const float* W_out  = (const float*)d_in[9];
  const float* g1     = (const float*)d_in[10];
  const float* b1     = (const float*)d_in[11];
  const float* W_ff1  = (const float*)d_in[12];
  const float* b_ff1  = (const float*)d_in[13];
  const float* W_ff2  = (const float*)d_in[14];
  const float* b_ff2  = (const float*)d_in[15];
  const float* g2     = (const float*)d_in[16];
  const float* b2     = (const float*)d_in[17];
  float* out = (float*)d_out;

  // linear layout (float offsets)
  float* ws = (float*)d_ws;
  u16*   xzb    = (u16*)ws;                 // 4,194,304 u16
  float* xdbl   = ws + 4194304;             //   131,072
  u16*   dtb    = (u16*)(ws + 4325376);     // 2,097,152 u16 (bf16 dt)
  float* apG    = ws + 6422528;             // 2,097,152
  float* hG     = ws + 8519680;             // 2,097,152
  float* rb     = ws + 11665408;            // 1,048,576
  u16*   bffh   = (u16*)(ws + 12713984);    // 2,097,152 u16
  u16*   ygb    = (u16*)(ws + 13762560);    // 2,097,152 u16
  u16*   ucb    = (u16*)(ws + 14811136);    // 2,097,152 u16
  u16*   brb    = (u16*)(ws + 15859712);    // 1,048,576 u16
  u16*   bdtr   = (u16*)(ws + 16384000);    //    65,536 u16
  u16*   bx     = (u16*)(ws + 16416768);    // 1,048,576 u16
  u16*   bW_in  = (u16*)(ws + 16941056);    // 1,048,576 u16
  u16*   bWxp   = (u16*)(ws + 17989632);    //    65,536 u16
  u16*   bW_dt  = (u16*)(ws + 18022400);    //    32,768 u16
  u16*   bW_out = (u16*)(ws + 18038784);    //   524,288 u16
  u16*   bW_ff1 = (u16*)(ws + 18300928);    //   524,288 u16
  u16*   bW_ff2 = (u16*)(ws + 18563072);    //   524,288 u16

  // 1. fused casts (x + 6 weights)
  cast_all<<<1840, 256, 0, stream>>>(x, W_in, W_xp, W_dt, W_out, W_ff1, W_ff2,
                                     bx, bW_in, bWxp, bW_dt, bW_out, bW_ff1, bW_ff2);
  // 2. in_proj -> bf16 xz   (512 blocks, 2/CU)
  gemm_t<128, 64, 0, u16><<<dim3(2 * DIN / 64, ML / 128), 256, 0, stream>>>(
      bx, bW_in, nullptr, xzb, ML, 2 * DIN, DD);
  // 3. conv + silu -> ucb (bf16)
  conv_silu<<<(ML * DIN) / 256, 256, 0, stream>>>(xzb, conv_w, conv_b, ucb);
  // 4. x_proj (bf16 MFMA), also emits bf16 dt_r
  xproj_mfma<<<ML / 128, 256, 0, stream>>>(ucb, bWxp, xdbl, bdtr);
  // 5. dt_proj GEMM + softplus -> bf16 dt
  gemm_t<128, 64, 3, u16><<<dim3(DIN / 64, ML / 128), 256, 0, stream>>>(
      bdtr, bW_dt, b_dt, dtb, ML, DIN, RNK);
  // 6. chunked scan (3 kernels; cooperative grid.sync costs ~55µs/sync on 8-XCD — R9)
  scan_p1<<<dim3(DIN / 256, NC, BB), 256, 0, stream>>>(dtb, ucb, xdbl, A_log, apG, hG);
  scan_p2<<<(NS * BDIN) / 128, 128, 0, stream>>>(apG, hG);
  scan_p3<<<dim3(DIN / 256, NC, BB), 256, 0, stream>>>(dtb, ucb, xzb, xdbl, A_log, D_skip,
                                                       hG, ygb);
  // 7. out_proj + LN1 fused -> rb (fp32) + brb (bf16)
  gemm_ln<0><<<ML / 64, 256, 0, stream>>>(ygb, bW_out, nullptr, x, nullptr, g1, b1, rb, brb);
  // 8. ff1 + bias + gelu -> bf16
  gemm_t<128, 64, 2, u16><<<dim3(DIN / 64, ML / 128), 256, 0, stream>>>(
      brb, bW_ff1, b_ff1, bffh, ML, DIN, DD);
  // 9. ff2 + final (silu + LN2 + x) fused -> out
  gemm_ln<1><<<ML / 64, 256, 0, stream>>>(bffh, bW_ff2, b_ff2, x, rb, g2, b2, out, nullptr);
}

// Round 12
// 174.855 us; speedup vs baseline: 2.0096x; 2.0096x over previous
//
#include <hip/hip_runtime.h>
#include <math.h>

#define BB 2
#define LL 1024
#define DD 512
#define DIN 1024      // d_inner
#define NS 16         // d_state
#define RNK 32        // dt_rank
#define ML (BB*LL)    // 2048 rows
#define CT 16         // scan chunk length
#define NC (LL/CT)    // 64 chunks
#define BDIN (BB*DIN) // 2048

typedef unsigned short u16;
typedef unsigned int u32;

__device__ __forceinline__ float sigmoidf_(float v) { return 1.f / (1.f + __expf(-v)); }
__device__ __forceinline__ float siluf_(float v) { return v * sigmoidf_(v); }
__device__ __forceinline__ u16 f2bf(float f) {
  union { float f; u32 u; } c; c.f = f;
  u32 r = c.u + 0x7fffu + ((c.u >> 16) & 1u);
  return (u16)(r >> 16);
}
__device__ __forceinline__ float bf2f(u16 x) {
  union { u32 u; float f; } c; c.u = (u32)x << 16;
  return c.f;
}

// load 8 consecutive elements as 8 bf16 packed in uint4 (converting if fp32)
template<typename T>
__device__ __forceinline__ uint4 ld8bf(const T* p);
template<> __device__ __forceinline__ uint4 ld8bf<u16>(const u16* p) {
  return *(const uint4*)p;
}
template<> __device__ __forceinline__ uint4 ld8bf<float>(const float* p) {
  float4 v0 = *(const float4*)p;
  float4 v1 = *(const float4*)(p + 4);
  union { u16 u[8]; uint4 v; } q;
  q.u[0] = f2bf(v0.x); q.u[1] = f2bf(v0.y); q.u[2] = f2bf(v0.z); q.u[3] = f2bf(v0.w);
  q.u[4] = f2bf(v1.x); q.u[5] = f2bf(v1.y); q.u[6] = f2bf(v1.z); q.u[7] = f2bf(v1.w);
  return q.v;
}

// ---------------- tiled bf16 MFMA GEMM: C[M,N] = A[M,K] @ W[N,K]^T ----------------
// TA/TW: u16 (bf16) or float (converted at stage time — numerics identical to pre-cast).
// EPI: 0 none, 1 +bias, 2 +bias+gelu, 3 +bias+softplus.  OT: float or u16
using bf16x8 = __attribute__((ext_vector_type(8))) short;
using f32x4  = __attribute__((ext_vector_type(4))) float;

template<int BM, int BN, int EPI, typename OT, typename TA, typename TW>
__global__ __launch_bounds__(256) void gemm_t(const TA* __restrict__ A,
                                              const TW* __restrict__ W,
                                              const float* __restrict__ bias,
                                              OT* __restrict__ C,
                                              int M, int N, int K)
{
  constexpr int WR = BM / 64;
  constexpr int WC = 4 / WR;
  constexpr int NW = BN / WC;       // cols per wave
  constexpr int JJ = NW / 16;       // 16-col fragments per wave
  constexpr int RB = BN / 64;       // B row-groups for staging
  __shared__ u16 As[BM][40];        // pad to 40: 2-way bank alias = free
  __shared__ u16 Bs[BN][40];
  const int bm = blockIdx.y * BM, bn = blockIdx.x * BN;
  const int tid = threadIdx.x;
  const int w = tid >> 6, l = tid & 63;
  const int wr = w / WC, wc = w % WC;
  const int lr = l & 15, lh = l >> 4;
  const int sr0 = tid >> 2, sc0 = tid & 3;
  f32x4 acc[4][JJ] = {};
  for (int k0 = 0; k0 < K; k0 += 32) {
    uint4 areg[WR], breg[RB];
#pragma unroll
    for (int i = 0; i < WR; ++i)
      areg[i] = ld8bf(&A[(size_t)(bm + sr0 + 64 * i) * K + k0 + sc0 * 8]);
#pragma unroll
    for (int i = 0; i < RB; ++i)
      breg[i] = ld8bf(&W[(size_t)(bn + sr0 + 64 * i) * K + k0 + sc0 * 8]);
    __syncthreads();
#pragma unroll
    for (int i = 0; i < WR; ++i) *(uint4*)&As[sr0 + 64 * i][sc0 * 8] = areg[i];
#pragma unroll
    for (int i = 0; i < RB; ++i) *(uint4*)&Bs[sr0 + 64 * i][sc0 * 8] = breg[i];
    __syncthreads();
    bf16x8 af[4], bfr[JJ];
#pragma unroll
    for (int i = 0; i < 4; ++i) af[i]  = *(bf16x8*)&As[wr * 64 + i * 16 + lr][lh * 8];
#pragma unroll
    for (int j = 0; j < JJ; ++j) bfr[j] = *(bf16x8*)&Bs[wc * NW + j * 16 + lr][lh * 8];
#pragma unroll
    for (int i = 0; i < 4; ++i)
#pragma unroll
      for (int j = 0; j < JJ; ++j)
        acc[i][j] = __builtin_amdgcn_mfma_f32_16x16x32_bf16(af[i], bfr[j], acc[i][j], 0, 0, 0);
  }
#pragma unroll
  for (int i = 0; i < 4; ++i) {
#pragma unroll
    for (int j = 0; j < JJ; ++j) {
      int col = bn + wc * NW + j * 16 + lr;
      float bv = (EPI >= 1) ? bias[col] : 0.f;
#pragma unroll
      for (int r = 0; r < 4; ++r) {
        int row = bm + wr * 64 + i * 16 + lh * 4 + r;
        float t = acc[i][j][r] + bv;
        if (EPI == 2) t = 0.5f * t * (1.f + erff(t * 0.70710678118654752f));
        if (EPI == 3) t = fmaxf(t, 0.f) + log1pf(__expf(-fabsf(t)));
        if constexpr (sizeof(OT) == 2) C[(size_t)row * N + col] = (OT)f2bf(t);
        else                           C[(size_t)row * N + col] = (OT)t;
      }
    }
  }
}

// ---------------- x_proj via MFMA: xdbl[M,64] = ucb @ W_xp^T (+ bf16 dt_r copy) ----------------
__global__ __launch_bounds__(256) void xproj_mfma(const u16* __restrict__ A,
                                                  const float* __restrict__ W,
                                                  float* __restrict__ C,
                                                  u16* __restrict__ bdtr)
{
  __shared__ u16 As[128][40];
  __shared__ u16 Bs[64][40];
  const int bm = blockIdx.x * 128;
  const int tid = threadIdx.x;
  const int w = tid >> 6, l = tid & 63;
  const int lr = l & 15, lh = l >> 4;
  const int sr0 = tid >> 2, sc0 = tid & 3;
  f32x4 acc[2][4] = {};
  for (int k0 = 0; k0 < DIN; k0 += 32) {
    uint4 a0 = ld8bf(&A[(size_t)(bm + sr0) * DIN + k0 + sc0 * 8]);
    uint4 a1 = ld8bf(&A[(size_t)(bm + sr0 + 64) * DIN + k0 + sc0 * 8]);
    uint4 b0;
    if (sr0 < 64) b0 = ld8bf(&W[(size_t)sr0 * DIN + k0 + sc0 * 8]);
    __syncthreads();
    *(uint4*)&As[sr0][sc0 * 8] = a0;
    *(uint4*)&As[sr0 + 64][sc0 * 8] = a1;
    if (sr0 < 64) *(uint4*)&Bs[sr0][sc0 * 8] = b0;
    __syncthreads();
    bf16x8 af[2], bfr[4];
#pragma unroll
    for (int i = 0; i < 2; ++i) af[i]  = *(bf16x8*)&As[w * 32 + i * 16 + lr][lh * 8];
#pragma unroll
    for (int j = 0; j < 4; ++j) bfr[j] = *(bf16x8*)&Bs[j * 16 + lr][lh * 8];
#pragma unroll
    for (int i = 0; i < 2; ++i)
#pragma unroll
      for (int j = 0; j < 4; ++j)
        acc[i][j] = __builtin_amdgcn_mfma_f32_16x16x32_bf16(af[i], bfr[j], acc[i][j], 0, 0, 0);
  }
#pragma unroll
  for (int i = 0; i < 2; ++i)
#pragma unroll
    for (int j = 0; j < 4; ++j) {
      int col = j * 16 + lr;
#pragma unroll
      for (int r = 0; r < 4; ++r) {
        int row = bm + w * 32 + i * 16 + lh * 4 + r;
        float v = acc[i][j][r];
        C[(size_t)row * 64 + col] = v;
        if (j < 2) bdtr[(size_t)row * RNK + col] = f2bf(v);   // dt_r cols 0..31
      }
    }
}

// ---------------- depthwise causal conv (K=4) + SiLU; bf16 in (xzb), bf16 out ----------------
__global__ __launch_bounds__(256) void conv_silu(const u16* __restrict__ xzb,
                                                 const float* __restrict__ conv_w,
                                                 const float* __restrict__ conv_b,
                                                 u16* __restrict__ ucb)
{
  int idx = blockIdx.x * 256 + threadIdx.x;
  int d = idx & (DIN - 1);
  int bl = idx >> 10;
  int l = bl & (LL - 1);
  int b = bl >> 10;
  float acc = conv_b[d];
#pragma unroll
  for (int k = 0; k < 4; ++k) {
    int ls = l - 3 + k;
    float uv = (ls >= 0) ? bf2f(xzb[((size_t)(b * LL + ls)) * (2 * DIN) + d]) : 0.f;
    acc = fmaf(uv, conv_w[d * 4 + k], acc);
  }
  ucb[idx] = f2bf(siluf_(acc));
}

// ================= chunked selective scan, register-state (3 kernels) =================
// thread = one d, 16 n-states in VGPRs. state layout: [c][n][b*DIN+d]. dt is bf16.

__global__ __launch_bounds__(256) void scan_p1(const u16* __restrict__ dtb,
                                               const u16* __restrict__ ucb,
                                               const float* __restrict__ xdbl,
                                               const float* __restrict__ A_log,
                                               float* __restrict__ apG,
                                               float* __restrict__ hG)
{
  __shared__ float dts[CT][256];
  __shared__ float us[CT][256];
  __shared__ float Bs[CT][NS];
  const int d0 = blockIdx.x * 256, c = blockIdx.y, b = blockIdx.z;
  const int tid = threadIdx.x;
  const int t0 = c * CT;
  for (int i = tid; i < CT * 64; i += 256) {
    int r = i >> 6, col = (i & 63) * 4;
    size_t row = (size_t)(b * LL + t0 + r);
    ushort4 dv = *(const ushort4*)&dtb[row * DIN + d0 + col];
    float4 df = { bf2f(dv.x), bf2f(dv.y), bf2f(dv.z), bf2f(dv.w) };
    *(float4*)&dts[r][col] = df;
    ushort4 uv = *(const ushort4*)&ucb[row * DIN + d0 + col];
    float4 uf = { bf2f(uv.x), bf2f(uv.y), bf2f(uv.z), bf2f(uv.w) };
    *(float4*)&us[r][col] = uf;
  }
  { int r = tid >> 4, n = tid & 15;
    Bs[r][n] = xdbl[(size_t)(b * LL + t0 + r) * 64 + 32 + n]; }
  __syncthreads();
  const int d = d0 + tid;
  float Ad[NS];
#pragma unroll
  for (int n = 0; n < NS; ++n) Ad[n] = -__expf(A_log[d * NS + n]);
  float h[NS] = {};
  float sdt = 0.f;
#pragma unroll 4
  for (int t = 0; t < CT; ++t) {
    float dtv = dts[t][tid];
    float dtu = dtv * us[t][tid];
    sdt += dtv;
    float4 B0 = *(float4*)&Bs[t][0],  B1 = *(float4*)&Bs[t][4];
    float4 B2 = *(float4*)&Bs[t][8],  B3 = *(float4*)&Bs[t][12];
    float Bq[NS] = { B0.x, B0.y, B0.z, B0.w, B1.x, B1.y, B1.z, B1.w,
                     B2.x, B2.y, B2.z, B2.w, B3.x, B3.y, B3.z, B3.w };
#pragma unroll
    for (int n = 0; n < NS; ++n) {
      float a = __expf(dtv * Ad[n]);
      h[n] = fmaf(a, h[n], dtu * Bq[n]);
    }
  }
  const int bd = b * DIN + d;
#pragma unroll
  for (int n = 0; n < NS; ++n) {
    apG[((size_t)c * NS + n) * BDIN + bd] = __expf(Ad[n] * sdt);
    hG [((size_t)c * NS + n) * BDIN + bd] = h[n];
  }
}

__global__ __launch_bounds__(128) void scan_p2(const float* __restrict__ apG,
                                               float* __restrict__ hG)
{
  const int idx = blockIdx.x * 128 + threadIdx.x;
  float H = 0.f;
#pragma unroll 16
  for (int c = 0; c < NC; ++c) {
    size_t o = (size_t)c * (NS * BDIN) + idx;
    float ap = apG[o];
    float hl = hG[o];
    hG[o] = H;
    H = fmaf(ap, H, hl);
  }
}

__global__ __launch_bounds__(256) void scan_p3(const u16* __restrict__ dtb,
                                               const u16* __restrict__ ucb,
                                               const u16* __restrict__ xzb,
                                               const float* __restrict__ xdbl,
                                               const float* __restrict__ A_log,
                                               const float* __restrict__ D_skip,
                                               const float* __restrict__ hG,
                                               u16* __restrict__ ygb)
{
  __shared__ float dts[CT][256];
  __shared__ float us[CT][256];
  __shared__ float zs[CT][256];
  __shared__ float Bs[CT][NS];
  __shared__ float Cs[CT][NS];
  const int d0 = blockIdx.x * 256, c = blockIdx.y, b = blockIdx.z;
  const int tid = threadIdx.x;
  const int t0 = c * CT;
  for (int i = tid; i < CT * 64; i += 256) {
    int r = i >> 6, col = (i & 63) * 4;
    size_t row = (size_t)(b * LL + t0 + r);
    ushort4 dv = *(const ushort4*)&dtb[row * DIN + d0 + col];
    float4 df = { bf2f(dv.x), bf2f(dv.y), bf2f(dv.z), bf2f(dv.w) };
    *(float4*)&dts[r][col] = df;
    ushort4 uv = *(const ushort4*)&ucb[row * DIN + d0 + col];
    float4 uf = { bf2f(uv.x), bf2f(uv.y), bf2f(uv.z), bf2f(uv.w) };
    *(float4*)&us[r][col] = uf;
    ushort4 zv = *(const ushort4*)&xzb[row * (2 * DIN) + DIN + d0 + col];
    float4 zf = { bf2f(zv.x), bf2f(zv.y), bf2f(zv.z), bf2f(zv.w) };
    *(float4*)&zs[r][col] = zf;
  }
  { int r = tid >> 4, n = tid & 15;
    size_t row = (size_t)(b * LL + t0 + r);
    Bs[r][n] = xdbl[row * 64 + 32 + n];
    Cs[r][n] = xdbl[row * 64 + 48 + n]; }
  __syncthreads();
  const int d = d0 + tid;
  const int bd = b * DIN + d;
  float Ad[NS];
#pragma unroll
  for (int n = 0; n < NS; ++n) Ad[n] = -__expf(A_log[d * NS + n]);
  const float Dd = D_skip[d];
  float h[NS];
#pragma unroll
  for (int n = 0; n < NS; ++n) h[n] = hG[((size_t)c * NS + n) * BDIN + bd];
#pragma unroll 2
  for (int t = 0; t < CT; ++t) {
    float dtv = dts[t][tid];
    float ucv = us[t][tid];
    float dtu = dtv * ucv;
    float4 B0 = *(float4*)&Bs[t][0],  B1 = *(float4*)&Bs[t][4];
    float4 B2 = *(float4*)&Bs[t][8],  B3 = *(float4*)&Bs[t][12];
    float4 C0 = *(float4*)&Cs[t][0],  C1 = *(float4*)&Cs[t][4];
    float4 C2 = *(float4*)&Cs[t][8],  C3 = *(float4*)&Cs[t][12];
    float Bq[NS] = { B0.x, B0.y, B0.z, B0.w, B1.x, B1.y, B1.z, B1.w,
                     B2.x, B2.y, B2.z, B2.w, B3.x, B3.y, B3.z, B3.w };
    float Cq[NS] = { C0.x, C0.y, C0.z, C0.w, C1.x, C1.y, C1.z, C1.w,
                     C2.x, C2.y, C2.z, C2.w, C3.x, C3.y, C3.z, C3.w };
    float y = 0.f;
#pragma unroll
    for (int n = 0; n < NS; ++n) {
      float a = __expf(dtv * Ad[n]);
      h[n] = fmaf(a, h[n], dtu * Bq[n]);
      y = fmaf(h[n], Cq[n], y);
    }
    float o = fmaf(ucv, Dd, y) * siluf_(zs[t][tid]);
    ygb[(size_t)(b * LL + t0 + t) * DIN + d0 + tid] = f2bf(o);
  }
}

// ---------------- LN1: r = layernorm(x - m)*g1 + b1, dual fp32+bf16 out ----------------
__global__ __launch_bounds__(256) void ln1_kernel(const float* __restrict__ x,
                                                  const float* __restrict__ m,
                                                  const float* __restrict__ g,
                                                  const float* __restrict__ b,
                                                  float* __restrict__ r,
                                                  u16* __restrict__ rbf)
{
  int row = blockIdx.x;
  int tid = threadIdx.x;
  size_t base = (size_t)row * DD;
  float2 xv = *(const float2*)&x[base + tid * 2];
  float2 mv = *(const float2*)&m[base + tid * 2];
  float v0 = xv.x - mv.x, v1 = xv.y - mv.y;
  float s = v0 + v1, ss = v0 * v0 + v1 * v1;
#pragma unroll
  for (int off = 32; off; off >>= 1) { s += __shfl_down(s, off, 64); ss += __shfl_down(ss, off, 64); }
  __shared__ float sm[8];
  int w = tid >> 6;
  if ((tid & 63) == 0) { sm[w] = s; sm[4 + w] = ss; }
  __syncthreads();
  float S = sm[0] + sm[1] + sm[2] + sm[3];
  float SS = sm[4] + sm[5] + sm[6] + sm[7];
  float mean = S * (1.f / DD);
  float var = SS * (1.f / DD) - mean * mean;
  float rstd = rsqrtf(var + 1e-5f);
  float2 gv = *(const float2*)&g[tid * 2];
  float2 bv = *(const float2*)&b[tid * 2];
  float2 o;
  o.x = (v0 - mean) * rstd * gv.x + bv.x;
  o.y = (v1 - mean) * rstd * gv.y + bv.y;
  *(float2*)&r[base + tid * 2] = o;
  u32 pk = (u32)f2bf(o.x) | ((u32)f2bf(o.y) << 16);
  *(u32*)&rbf[base + tid * 2] = pk;
}

// ---------------- final: out = layernorm(silu(r - ff)) * g2 + b2 + x ----------------
__global__ __launch_bounds__(256) void final_kernel(const float* __restrict__ r,
                                                    const float* __restrict__ ff,
                                                    const float* __restrict__ x,
                                                    const float* __restrict__ g,
                                                    const float* __restrict__ b,
                                                    float* __restrict__ out)
{
  int row = blockIdx.x;
  int tid = threadIdx.x;
  size_t base = (size_t)row * DD;
  float2 rv = *(const float2*)&r[base + tid * 2];
  float2 fv = *(const float2*)&ff[base + tid * 2];
  float v0 = rv.x - fv.x, v1 = rv.y - fv.y;
  v0 = siluf_(v0); v1 = siluf_(v1);
  float s = v0 + v1, ss = v0 * v0 + v1 * v1;
#pragma unroll
  for (int off = 32; off; off >>= 1) { s += __shfl_down(s, off, 64); ss += __shfl_down(ss, off, 64); }
  __shared__ float sm[8];
  int w = tid >> 6;
  if ((tid & 63) == 0) { sm[w] = s; sm[4 + w] = ss; }
  __syncthreads();
  float S = sm[0] + sm[1] + sm[2] + sm[3];
  float SS = sm[4] + sm[5] + sm[6] + sm[7];
  float mean = S * (1.f / DD);
  float var = SS * (1.f / DD) - mean * mean;
  float rstd = rsqrtf(var + 1e-5f);
  float2 gv = *(const float2*)&g[tid * 2];
  float2 bv = *(const float2*)&b[tid * 2];
  float2 xv = *(const float2*)&x[base + tid * 2];
  float2 o;
  o.x = (v0 - mean) * rstd * gv.x + bv.x + xv.x;
  o.y = (v1 - mean) * rstd * gv.y + bv.y + xv.y;
  *(float2*)&out[base + tid * 2] = o;
}

extern "C" void kernel_launch(void* const* d_in, const int* in_sizes, int n_in,
                              void* d_out, int out_size, void* d_ws, size_t ws_size,
                              hipStream_t stream)
{
  const float* x      = (const float*)d_in[0];
  const float* W_in   = (const float*)d_in[1];
  const float* conv_w = (const float*)d_in[2];
  const float* conv_b = (const float*)d_in[3];
  const float* W_xp   = (const float*)d_in[4];
  const float* W_dt   = (const float*)d_in[5];
  const float* b_dt   = (const float*)d_in[6];
  const float* A_log  = (const float*)d_in[7];
  const float* D_skip = (const float*)d_in[8];
  const float* W_out  = (const float*)d_in[9];
  const float* g1     = (const float*)d_in[10];
  const float* b1     = (const float*)d_in[11];
  const float* W_ff1  = (const float*)d_in[12];
  const float* b_ff1  = (const float*)d_in[13];
  const float* W_ff2  = (const float*)d_in[14];
  const float* b_ff2  = (const float*)d_in[15];
  const float* g2     = (const float*)d_in[16];
  const float* b2     = (const float*)d_in[17];
  float* out = (float*)d_out;

  // compact linear layout (~53 MB, float offsets); no pre-cast buffers needed
  float* ws = (float*)d_ws;
  u16*   xzb  = (u16*)ws;                  // 4,194,304 u16 (2,097,152 f)
  float* xdbl = ws + 2097152;              //   131,072 f
  u16*   dtb  = (u16*)(ws + 2228224);      // 2,097,152 u16 (1,048,576 f)
  float* apG  = ws + 3276800;              // 2,097,152 f
  float* hG   = ws + 5373952;              // 2,097,152 f
  float* mb   = ws + 7471104;              // 1,048,576 f
  float* rb   = ws + 8519680;              // 1,048,576 f
  u16*   bffh = (u16*)(ws + 9568256);      // 2,097,152 u16
  u16*   ygb  = (u16*)(ws + 10616832);     // 2,097,152 u16
  u16*   ucb  = (u16*)(ws + 11665408);     // 2,097,152 u16
  u16*   brb  = (u16*)(ws + 12713984);     // 1,048,576 u16
  u16*   bdtr = (u16*)(ws + 13238272);     //    65,536 u16

  // 1. in_proj -> bf16 xz  (fp32 A/W converted in staging; 512 blocks, 2/CU)
  gemm_t<128, 64, 0, u16, float, float><<<dim3(2 * DIN / 64, ML / 128), 256, 0, stream>>>(
      x, W_in, nullptr, xzb, ML, 2 * DIN, DD);
  // 2. conv + silu -> ucb (bf16)
  conv_silu<<<(ML * DIN) / 256, 256, 0, stream>>>(xzb, conv_w, conv_b, ucb);
  // 3. x_proj (bf16 A, fp32 W), also emits bf16 dt_r
  xproj_mfma<<<ML / 128, 256, 0, stream>>>(ucb, W_xp, xdbl, bdtr);
  // 4. dt_proj GEMM + softplus -> bf16 dt
  gemm_t<128, 64, 3, u16, u16, float><<<dim3(DIN / 64, ML / 128), 256, 0, stream>>>(
      bdtr, W_dt, b_dt, dtb, ML, DIN, RNK);
  // 5. chunked scan (3 kernels; R9: cooperative grid.sync ≈55µs/sync on 8-XCD — avoid)
  scan_p1<<<dim3(DIN / 256, NC, BB), 256, 0, stream>>>(dtb, ucb, xdbl, A_log, apG, hG);
  scan_p2<<<(NS * BDIN) / 128, 128, 0, stream>>>(apG, hG);
  scan_p3<<<dim3(DIN / 256, NC, BB), 256, 0, stream>>>(dtb, ucb, xzb, xdbl, A_log, D_skip,
                                                       hG, ygb);
  // 6. out_proj: mb = yg @ W_out^T  (256 blocks)
  gemm_t<64, 64, 0, float, u16, float><<<dim3(DD / 64, ML / 64), 256, 0, stream>>>(
      ygb, W_out, nullptr, mb, ML, DD, DIN);
  // 7. LN1 (fp32 + bf16 out)
  ln1_kernel<<<ML, 256, 0, stream>>>(x, mb, g1, b1, rb, brb);
  // 8. ff1 + bias + gelu -> bf16  (256 blocks)
  gemm_t<128, 64, 2, u16, u16, float><<<dim3(DIN / 64, ML / 128), 256, 0, stream>>>(
      brb, W_ff1, b_ff1, bffh, ML, DIN, DD);
  // 9. ff2 + bias -> mb  (256 blocks)
  gemm_t<64, 64, 1, float, u16, float><<<dim3(DD / 64, ML / 64), 256, 0, stream>>>(
      bffh, W_ff2, b_ff2, mb, ML, DD, DIN);
  // 10. final
  final_kernel<<<ML, 256, 0, stream>>>(rb, mb, x, g2, b2, out);
}

// Round 13
// 159.758 us; speedup vs baseline: 2.1995x; 1.0945x over previous
//
#include <hip/hip_runtime.h>
#include <math.h>

#define BB 2
#define LL 1024
#define DD 512
#define DIN 1024      // d_inner
#define NS 16         // d_state
#define RNK 32        // dt_rank
#define ML (BB*LL)    // 2048 rows
#define CT 16         // scan chunk length
#define NC (LL/CT)    // 64 chunks
#define BDIN (BB*DIN) // 2048

typedef unsigned short u16;
typedef unsigned int u32;

__device__ __forceinline__ float sigmoidf_(float v) { return 1.f / (1.f + __expf(-v)); }
__device__ __forceinline__ float siluf_(float v) { return v * sigmoidf_(v); }
__device__ __forceinline__ u16 f2bf(float f) {
  union { float f; u32 u; } c; c.f = f;
  u32 r = c.u + 0x7fffu + ((c.u >> 16) & 1u);
  return (u16)(r >> 16);
}
__device__ __forceinline__ float bf2f(u16 x) {
  union { u32 u; float f; } c; c.u = (u32)x << 16;
  return c.f;
}

// load 8 consecutive elements as 8 bf16 packed in uint4 (converting if fp32)
template<typename T>
__device__ __forceinline__ uint4 ld8bf(const T* p);
template<> __device__ __forceinline__ uint4 ld8bf<u16>(const u16* p) {
  return *(const uint4*)p;
}
template<> __device__ __forceinline__ uint4 ld8bf<float>(const float* p) {
  float4 v0 = *(const float4*)p;
  float4 v1 = *(const float4*)(p + 4);
  union { u16 u[8]; uint4 v; } q;
  q.u[0] = f2bf(v0.x); q.u[1] = f2bf(v0.y); q.u[2] = f2bf(v0.z); q.u[3] = f2bf(v0.w);
  q.u[4] = f2bf(v1.x); q.u[5] = f2bf(v1.y); q.u[6] = f2bf(v1.z); q.u[7] = f2bf(v1.w);
  return q.v;
}

// ---------------- tiled bf16 MFMA GEMM: C[M,N] = A[M,K] @ W[N,K]^T ----------------
// BK in {32,64}: K-elems staged per barrier pair (BK=64 halves syncthreads count).
// kk-outer MFMA loop keeps accumulation order identical to BK=32 (bit-identical).
// TA/TW: u16 (bf16) or float (converted at stage time).
// EPI: 0 none, 1 +bias, 2 +bias+gelu, 3 +bias+softplus.  OT: float or u16
using bf16x8 = __attribute__((ext_vector_type(8))) short;
using f32x4  = __attribute__((ext_vector_type(4))) float;

template<int BM, int BN, int BK, int EPI, typename OT, typename TA, typename TW>
__global__ __launch_bounds__(256) void gemm_t(const TA* __restrict__ A,
                                              const TW* __restrict__ W,
                                              const float* __restrict__ bias,
                                              OT* __restrict__ C,
                                              int M, int N, int K)
{
  constexpr int WR = BM / 64;
  constexpr int WC = 4 / WR;
  constexpr int NW = BN / WC;       // cols per wave
  constexpr int JJ = NW / 16;       // 16-col fragments per wave
  constexpr int RB = BN / 64;       // B row-groups for staging
  constexpr int KK = BK / 32;       // 32-col K-chunks per stage
  __shared__ u16 As[BM][BK + 8];    // +8 pad: ≤2-way bank alias (free, m136)
  __shared__ u16 Bs[BN][BK + 8];
  const int bm = blockIdx.y * BM, bn = blockIdx.x * BN;
  const int tid = threadIdx.x;
  const int w = tid >> 6, l = tid & 63;
  const int wr = w / WC, wc = w % WC;
  const int lr = l & 15, lh = l >> 4;
  const int sr0 = tid >> 2, sc0 = tid & 3;
  f32x4 acc[4][JJ] = {};
  for (int k0 = 0; k0 < K; k0 += BK) {
    uint4 areg[WR][KK], breg[RB][KK];
#pragma unroll
    for (int i = 0; i < WR; ++i)
#pragma unroll
      for (int kk = 0; kk < KK; ++kk)
        areg[i][kk] = ld8bf(&A[(size_t)(bm + sr0 + 64 * i) * K + k0 + kk * 32 + sc0 * 8]);
#pragma unroll
    for (int i = 0; i < RB; ++i)
#pragma unroll
      for (int kk = 0; kk < KK; ++kk)
        breg[i][kk] = ld8bf(&W[(size_t)(bn + sr0 + 64 * i) * K + k0 + kk * 32 + sc0 * 8]);
    __syncthreads();
#pragma unroll
    for (int i = 0; i < WR; ++i)
#pragma unroll
      for (int kk = 0; kk < KK; ++kk)
        *(uint4*)&As[sr0 + 64 * i][kk * 32 + sc0 * 8] = areg[i][kk];
#pragma unroll
    for (int i = 0; i < RB; ++i)
#pragma unroll
      for (int kk = 0; kk < KK; ++kk)
        *(uint4*)&Bs[sr0 + 64 * i][kk * 32 + sc0 * 8] = breg[i][kk];
    __syncthreads();
    bf16x8 af[KK][4], bfr[KK][JJ];
#pragma unroll
    for (int kk = 0; kk < KK; ++kk) {
#pragma unroll
      for (int i = 0; i < 4; ++i)  af[kk][i]  = *(bf16x8*)&As[wr * 64 + i * 16 + lr][kk * 32 + lh * 8];
#pragma unroll
      for (int j = 0; j < JJ; ++j) bfr[kk][j] = *(bf16x8*)&Bs[wc * NW + j * 16 + lr][kk * 32 + lh * 8];
    }
#pragma unroll
    for (int kk = 0; kk < KK; ++kk)
#pragma unroll
      for (int i = 0; i < 4; ++i)
#pragma unroll
        for (int j = 0; j < JJ; ++j)
          acc[i][j] = __builtin_amdgcn_mfma_f32_16x16x32_bf16(af[kk][i], bfr[kk][j], acc[i][j], 0, 0, 0);
  }
#pragma unroll
  for (int i = 0; i < 4; ++i) {
#pragma unroll
    for (int j = 0; j < JJ; ++j) {
      int col = bn + wc * NW + j * 16 + lr;
      float bv = (EPI >= 1) ? bias[col] : 0.f;
#pragma unroll
      for (int r = 0; r < 4; ++r) {
        int row = bm + wr * 64 + i * 16 + lh * 4 + r;
        float t = acc[i][j][r] + bv;
        if (EPI == 2) t = 0.5f * t * (1.f + erff(t * 0.70710678118654752f));
        if (EPI == 3) t = fmaxf(t, 0.f) + log1pf(__expf(-fabsf(t)));
        if constexpr (sizeof(OT) == 2) C[(size_t)row * N + col] = (OT)f2bf(t);
        else                           C[(size_t)row * N + col] = (OT)t;
      }
    }
  }
}

// ---------------- x_proj via MFMA: xdbl[M,64] = ucb @ W_xp^T (+ bf16 dt_r copy) ----------------
__global__ __launch_bounds__(256) void xproj_mfma(const u16* __restrict__ A,
                                                  const float* __restrict__ W,
                                                  float* __restrict__ C,
                                                  u16* __restrict__ bdtr)
{
  __shared__ u16 As[128][40];
  __shared__ u16 Bs[64][40];
  const int bm = blockIdx.x * 128;
  const int tid = threadIdx.x;
  const int w = tid >> 6, l = tid & 63;
  const int lr = l & 15, lh = l >> 4;
  const int sr0 = tid >> 2, sc0 = tid & 3;
  f32x4 acc[2][4] = {};
  for (int k0 = 0; k0 < DIN; k0 += 32) {
    uint4 a0 = ld8bf(&A[(size_t)(bm + sr0) * DIN + k0 + sc0 * 8]);
    uint4 a1 = ld8bf(&A[(size_t)(bm + sr0 + 64) * DIN + k0 + sc0 * 8]);
    uint4 b0;
    if (sr0 < 64) b0 = ld8bf(&W[(size_t)sr0 * DIN + k0 + sc0 * 8]);
    __syncthreads();
    *(uint4*)&As[sr0][sc0 * 8] = a0;
    *(uint4*)&As[sr0 + 64][sc0 * 8] = a1;
    if (sr0 < 64) *(uint4*)&Bs[sr0][sc0 * 8] = b0;
    __syncthreads();
    bf16x8 af[2], bfr[4];
#pragma unroll
    for (int i = 0; i < 2; ++i) af[i]  = *(bf16x8*)&As[w * 32 + i * 16 + lr][lh * 8];
#pragma unroll
    for (int j = 0; j < 4; ++j) bfr[j] = *(bf16x8*)&Bs[j * 16 + lr][lh * 8];
#pragma unroll
    for (int i = 0; i < 2; ++i)
#pragma unroll
      for (int j = 0; j < 4; ++j)
        acc[i][j] = __builtin_amdgcn_mfma_f32_16x16x32_bf16(af[i], bfr[j], acc[i][j], 0, 0, 0);
  }
#pragma unroll
  for (int i = 0; i < 2; ++i)
#pragma unroll
    for (int j = 0; j < 4; ++j) {
      int col = j * 16 + lr;
#pragma unroll
      for (int r = 0; r < 4; ++r) {
        int row = bm + w * 32 + i * 16 + lh * 4 + r;
        float v = acc[i][j][r];
        C[(size_t)row * 64 + col] = v;
        if (j < 2) bdtr[(size_t)row * RNK + col] = f2bf(v);   // dt_r cols 0..31
      }
    }
}

// ---------------- depthwise causal conv (K=4) + SiLU; vectorized 8 d/thread ----------------
__global__ __launch_bounds__(256) void conv_silu8(const u16* __restrict__ xzb,
                                                  const float* __restrict__ conv_w,
                                                  const float* __restrict__ conv_b,
                                                  u16* __restrict__ ucb)
{
  int gid = blockIdx.x * 256 + threadIdx.x;      // over ML*DIN/8 = 262144
  int d8 = (gid & (DIN / 8 - 1)) * 8;
  int bl = gid >> 7;                              // b*L + l
  int l = bl & (LL - 1);
  int b = bl >> 10;
  float acc[8];
  {
    float4 c0 = *(const float4*)&conv_b[d8];
    float4 c1 = *(const float4*)&conv_b[d8 + 4];
    acc[0] = c0.x; acc[1] = c0.y; acc[2] = c0.z; acc[3] = c0.w;
    acc[4] = c1.x; acc[5] = c1.y; acc[6] = c1.z; acc[7] = c1.w;
  }
  float4 wv[8];
#pragma unroll
  for (int j = 0; j < 8; ++j) wv[j] = *(const float4*)&conv_w[(d8 + j) * 4];
#pragma unroll
  for (int k = 0; k < 4; ++k) {
    int ls = l - 3 + k;
    if (ls >= 0) {
      const u16* p = &xzb[((size_t)(b * LL + ls)) * (2 * DIN) + d8];
      ushort4 a0 = *(const ushort4*)p;
      ushort4 a1 = *(const ushort4*)(p + 4);
      float xv[8] = { bf2f(a0.x), bf2f(a0.y), bf2f(a0.z), bf2f(a0.w),
                      bf2f(a1.x), bf2f(a1.y), bf2f(a1.z), bf2f(a1.w) };
      const float* wk = (const float*)wv;
#pragma unroll
      for (int j = 0; j < 8; ++j) acc[j] = fmaf(xv[j], wk[j * 4 + k], acc[j]);
    }
  }
  union { u16 u[8]; uint4 v; } o;
#pragma unroll
  for (int j = 0; j < 8; ++j) o.u[j] = f2bf(siluf_(acc[j]));
  *(uint4*)&ucb[(size_t)bl * DIN + d8] = o.v;
}

// ================= chunked selective scan, register-state (3 kernels) =================
// thread = one d, 16 n-states in VGPRs. state layout: [c][n][b*DIN+d]. dt is bf16.

__global__ __launch_bounds__(256) void scan_p1(const u16* __restrict__ dtb,
                                               const u16* __restrict__ ucb,
                                               const float* __restrict__ xdbl,
                                               const float* __restrict__ A_log,
                                               float* __restrict__ apG,
                                               float* __restrict__ hG)
{
  __shared__ float dts[CT][256];
  __shared__ float us[CT][256];
  __shared__ float Bs[CT][NS];
  const int d0 = blockIdx.x * 256, c = blockIdx.y, b = blockIdx.z;
  const int tid = threadIdx.x;
  const int t0 = c * CT;
  for (int i = tid; i < CT * 64; i += 256) {
    int r = i >> 6, col = (i & 63) * 4;
    size_t row = (size_t)(b * LL + t0 + r);
    ushort4 dv = *(const ushort4*)&dtb[row * DIN + d0 + col];
    float4 df = { bf2f(dv.x), bf2f(dv.y), bf2f(dv.z), bf2f(dv.w) };
    *(float4*)&dts[r][col] = df;
    ushort4 uv = *(const ushort4*)&ucb[row * DIN + d0 + col];
    float4 uf = { bf2f(uv.x), bf2f(uv.y), bf2f(uv.z), bf2f(uv.w) };
    *(float4*)&us[r][col] = uf;
  }
  { int r = tid >> 4, n = tid & 15;
    Bs[r][n] = xdbl[(size_t)(b * LL + t0 + r) * 64 + 32 + n]; }
  __syncthreads();
  const int d = d0 + tid;
  float Ad[NS];
#pragma unroll
  for (int n = 0; n < NS; ++n) Ad[n] = -__expf(A_log[d * NS + n]);
  float h[NS] = {};
  float sdt = 0.f;
#pragma unroll 4
  for (int t = 0; t < CT; ++t) {
    float dtv = dts[t][tid];
    float dtu = dtv * us[t][tid];
    sdt += dtv;
    float4 B0 = *(float4*)&Bs[t][0],  B1 = *(float4*)&Bs[t][4];
    float4 B2 = *(float4*)&Bs[t][8],  B3 = *(float4*)&Bs[t][12];
    float Bq[NS] = { B0.x, B0.y, B0.z, B0.w, B1.x, B1.y, B1.z, B1.w,
                     B2.x, B2.y, B2.z, B2.w, B3.x, B3.y, B3.z, B3.w };
#pragma unroll
    for (int n = 0; n < NS; ++n) {
      float a = __expf(dtv * Ad[n]);
      h[n] = fmaf(a, h[n], dtu * Bq[n]);
    }
  }
  const int bd = b * DIN + d;
#pragma unroll
  for (int n = 0; n < NS; ++n) {
    apG[((size_t)c * NS + n) * BDIN + bd] = __expf(Ad[n] * sdt);
    hG [((size_t)c * NS + n) * BDIN + bd] = h[n];
  }
}

__global__ __launch_bounds__(128) void scan_p2(const float* __restrict__ apG,
                                               float* __restrict__ hG)
{
  const int idx = blockIdx.x * 128 + threadIdx.x;
  float H = 0.f;
#pragma unroll 16
  for (int c = 0; c < NC; ++c) {
    size_t o = (size_t)c * (NS * BDIN) + idx;
    float ap = apG[o];
    float hl = hG[o];
    hG[o] = H;
    H = fmaf(ap, H, hl);
  }
}

__global__ __launch_bounds__(256) void scan_p3(const u16* __restrict__ dtb,
                                               const u16* __restrict__ ucb,
                                               const u16* __restrict__ xzb,
                                               const float* __restrict__ xdbl,
                                               const float* __restrict__ A_log,
                                               const float* __restrict__ D_skip,
                                               const float* __restrict__ hG,
                                               u16* __restrict__ ygb)
{
  __shared__ float dts[CT][256];
  __shared__ float us[CT][256];
  __shared__ float zs[CT][256];
  __shared__ float Bs[CT][NS];
  __shared__ float Cs[CT][NS];
  const int d0 = blockIdx.x * 256, c = blockIdx.y, b = blockIdx.z;
  const int tid = threadIdx.x;
  const int t0 = c * CT;
  for (int i = tid; i < CT * 64; i += 256) {
    int r = i >> 6, col = (i & 63) * 4;
    size_t row = (size_t)(b * LL + t0 + r);
    ushort4 dv = *(const ushort4*)&dtb[row * DIN + d0 + col];
    float4 df = { bf2f(dv.x), bf2f(dv.y), bf2f(dv.z), bf2f(dv.w) };
    *(float4*)&dts[r][col] = df;
    ushort4 uv = *(const ushort4*)&ucb[row * DIN + d0 + col];
    float4 uf = { bf2f(uv.x), bf2f(uv.y), bf2f(uv.z), bf2f(uv.w) };
    *(float4*)&us[r][col] = uf;
    ushort4 zv = *(const ushort4*)&xzb[row * (2 * DIN) + DIN + d0 + col];
    float4 zf = { bf2f(zv.x), bf2f(zv.y), bf2f(zv.z), bf2f(zv.w) };
    *(float4*)&zs[r][col] = zf;
  }
  { int r = tid >> 4, n = tid & 15;
    size_t row = (size_t)(b * LL + t0 + r);
    Bs[r][n] = xdbl[row * 64 + 32 + n];
    Cs[r][n] = xdbl[row * 64 + 48 + n]; }
  __syncthreads();
  const int d = d0 + tid;
  const int bd = b * DIN + d;
  float Ad[NS];
#pragma unroll
  for (int n = 0; n < NS; ++n) Ad[n] = -__expf(A_log[d * NS + n]);
  const float Dd = D_skip[d];
  float h[NS];
#pragma unroll
  for (int n = 0; n < NS; ++n) h[n] = hG[((size_t)c * NS + n) * BDIN + bd];
#pragma unroll 2
  for (int t = 0; t < CT; ++t) {
    float dtv = dts[t][tid];
    float ucv = us[t][tid];
    float dtu = dtv * ucv;
    float4 B0 = *(float4*)&Bs[t][0],  B1 = *(float4*)&Bs[t][4];
    float4 B2 = *(float4*)&Bs[t][8],  B3 = *(float4*)&Bs[t][12];
    float4 C0 = *(float4*)&Cs[t][0],  C1 = *(float4*)&Cs[t][4];
    float4 C2 = *(float4*)&Cs[t][8],  C3 = *(float4*)&Cs[t][12];
    float Bq[NS] = { B0.x, B0.y, B0.z, B0.w, B1.x, B1.y, B1.z, B1.w,
                     B2.x, B2.y, B2.z, B2.w, B3.x, B3.y, B3.z, B3.w };
    float Cq[NS] = { C0.x, C0.y, C0.z, C0.w, C1.x, C1.y, C1.z, C1.w,
                     C2.x, C2.y, C2.z, C2.w, C3.x, C3.y, C3.z, C3.w };
    float y = 0.f;
#pragma unroll
    for (int n = 0; n < NS; ++n) {
      float a = __expf(dtv * Ad[n]);
      h[n] = fmaf(a, h[n], dtu * Bq[n]);
      y = fmaf(h[n], Cq[n], y);
    }
    float o = fmaf(ucv, Dd, y) * siluf_(zs[t][tid]);
    ygb[(size_t)(b * LL + t0 + t) * DIN + d0 + tid] = f2bf(o);
  }
}

// ---------------- LN1: r = layernorm(x - m)*g1 + b1, dual fp32+bf16 out ----------------
__global__ __launch_bounds__(256) void ln1_kernel(const float* __restrict__ x,
                                                  const float* __restrict__ m,
                                                  const float* __restrict__ g,
                                                  const float* __restrict__ b,
                                                  float* __restrict__ r,
                                                  u16* __restrict__ rbf)
{
  int row = blockIdx.x;
  int tid = threadIdx.x;
  size_t base = (size_t)row * DD;
  float2 xv = *(const float2*)&x[base + tid * 2];
  float2 mv = *(const float2*)&m[base + tid * 2];
  float v0 = xv.x - mv.x, v1 = xv.y - mv.y;
  float s = v0 + v1, ss = v0 * v0 + v1 * v1;
#pragma unroll
  for (int off = 32; off; off >>= 1) { s += __shfl_down(s, off, 64); ss += __shfl_down(ss, off, 64); }
  __shared__ float sm[8];
  int w = tid >> 6;
  if ((tid & 63) == 0) { sm[w] = s; sm[4 + w] = ss; }
  __syncthreads();
  float S = sm[0] + sm[1] + sm[2] + sm[3];
  float SS = sm[4] + sm[5] + sm[6] + sm[7];
  float mean = S * (1.f / DD);
  float var = SS * (1.f / DD) - mean * mean;
  float rstd = rsqrtf(var + 1e-5f);
  float2 gv = *(const float2*)&g[tid * 2];
  float2 bv = *(const float2*)&b[tid * 2];
  float2 o;
  o.x = (v0 - mean) * rstd * gv.x + bv.x;
  o.y = (v1 - mean) * rstd * gv.y + bv.y;
  *(float2*)&r[base + tid * 2] = o;
  u32 pk = (u32)f2bf(o.x) | ((u32)f2bf(o.y) << 16);
  *(u32*)&rbf[base + tid * 2] = pk;
}

// ---------------- final: out = layernorm(silu(r - ff)) * g2 + b2 + x ----------------
__global__ __launch_bounds__(256) void final_kernel(const float* __restrict__ r,
                                                    const float* __restrict__ ff,
                                                    const float* __restrict__ x,
                                                    const float* __restrict__ g,
                                                    const float* __restrict__ b,
                                                    float* __restrict__ out)
{
  int row = blockIdx.x;
  int tid = threadIdx.x;
  size_t base = (size_t)row * DD;
  float2 rv = *(const float2*)&r[base + tid * 2];
  float2 fv = *(const float2*)&ff[base + tid * 2];
  float v0 = rv.x - fv.x, v1 = rv.y - fv.y;
  v0 = siluf_(v0); v1 = siluf_(v1);
  float s = v0 + v1, ss = v0 * v0 + v1 * v1;
#pragma unroll
  for (int off = 32; off; off >>= 1) { s += __shfl_down(s, off, 64); ss += __shfl_down(ss, off, 64); }
  __shared__ float sm[8];
  int w = tid >> 6;
  if ((tid & 63) == 0) { sm[w] = s; sm[4 + w] = ss; }
  __syncthreads();
  float S = sm[0] + sm[1] + sm[2] + sm[3];
  float SS = sm[4] + sm[5] + sm[6] + sm[7];
  float mean = S * (1.f / DD);
  float var = SS * (1.f / DD) - mean * mean;
  float rstd = rsqrtf(var + 1e-5f);
  float2 gv = *(const float2*)&g[tid * 2];
  float2 bv = *(const float2*)&b[tid * 2];
  float2 xv = *(const float2*)&x[base + tid * 2];
  float2 o;
  o.x = (v0 - mean) * rstd * gv.x + bv.x + xv.x;
  o.y = (v1 - mean) * rstd * gv.y + bv.y + xv.y;
  *(float2*)&out[base + tid * 2] = o;
}

extern "C" void kernel_launch(void* const* d_in, const int* in_sizes, int n_in,
                              void* d_out, int out_size, void* d_ws, size_t ws_size,
                              hipStream_t stream)
{
  const float* x      = (const float*)d_in[0];
  const float* W_in   = (const float*)d_in[1];
  const float* conv_w = (const float*)d_in[2];
  const float* conv_b = (const float*)d_in[3];
  const float* W_xp   = (const float*)d_in[4];
  const float* W_dt   = (const float*)d_in[5];
  const float* b_dt   = (const float*)d_in[6];
  const float* A_log  = (const float*)d_in[7];
  const float* D_skip = (const float*)d_in[8];
  const float* W_out  = (const float*)d_in[9];
  const float* g1     = (const float*)d_in[10];
  const float* b1     = (const float*)d_in[11];
  const float* W_ff1  = (const float*)d_in[12];
  const float* b_ff1  = (const float*)d_in[13];
  const float* W_ff2  = (const float*)d_in[14];
  const float* b_ff2  = (const float*)d_in[15];
  const float* g2     = (const float*)d_in[16];
  const float* b2     = (const float*)d_in[17];
  float* out = (float*)d_out;

  // compact linear layout (~53 MB, float offsets)
  float* ws = (float*)d_ws;
  u16*   xzb  = (u16*)ws;                  // 4,194,304 u16
  float* xdbl = ws + 2097152;              //   131,072 f
  u16*   dtb  = (u16*)(ws + 2228224);      // 2,097,152 u16
  float* apG  = ws + 3276800;              // 2,097,152 f
  float* hG   = ws + 5373952;              // 2,097,152 f
  float* mb   = ws + 7471104;              // 1,048,576 f
  float* rb   = ws + 8519680;              // 1,048,576 f
  u16*   bffh = (u16*)(ws + 9568256);      // 2,097,152 u16
  u16*   ygb  = (u16*)(ws + 10616832);     // 2,097,152 u16
  u16*   ucb  = (u16*)(ws + 11665408);     // 2,097,152 u16
  u16*   brb  = (u16*)(ws + 12713984);     // 1,048,576 u16
  u16*   bdtr = (u16*)(ws + 13238272);     //    65,536 u16

  // 1. in_proj -> bf16 xz  (BK=64: 8 K-iters; 512 blocks, 2/CU)
  gemm_t<128, 64, 64, 0, u16, float, float><<<dim3(2 * DIN / 64, ML / 128), 256, 0, stream>>>(
      x, W_in, nullptr, xzb, ML, 2 * DIN, DD);
  // 2. conv + silu -> ucb (vectorized, 8 d/thread, 1024 blocks)
  conv_silu8<<<(ML * DIN / 8) / 256, 256, 0, stream>>>(xzb, conv_w, conv_b, ucb);
  // 3. x_proj (bf16 A, fp32 W), also emits bf16 dt_r
  xproj_mfma<<<ML / 128, 256, 0, stream>>>(ucb, W_xp, xdbl, bdtr);
  // 4. dt_proj GEMM + softplus -> bf16 dt  (BK=32: K=RNK=32, single stage)
  gemm_t<128, 64, 32, 3, u16, u16, float><<<dim3(DIN / 64, ML / 128), 256, 0, stream>>>(
      bdtr, W_dt, b_dt, dtb, ML, DIN, RNK);
  // 5. chunked scan (3 kernels; R9: cooperative grid.sync ≈55µs/sync on 8-XCD — avoid)
  scan_p1<<<dim3(DIN / 256, NC, BB), 256, 0, stream>>>(dtb, ucb, xdbl, A_log, apG, hG);
  scan_p2<<<(NS * BDIN) / 128, 128, 0, stream>>>(apG, hG);
  scan_p3<<<dim3(DIN / 256, NC, BB), 256, 0, stream>>>(dtb, ucb, xzb, xdbl, A_log, D_skip,
                                                       hG, ygb);
  // 6. out_proj: mb = yg @ W_out^T  (BK=64: 16 K-iters; 256 blocks)
  gemm_t<64, 64, 64, 0, float, u16, float><<<dim3(DD / 64, ML / 64), 256, 0, stream>>>(
      ygb, W_out, nullptr, mb, ML, DD, DIN);
  // 7. LN1 (fp32 + bf16 out)
  ln1_kernel<<<ML, 256, 0, stream>>>(x, mb, g1, b1, rb, brb);
  // 8. ff1 + bias + gelu -> bf16  (BK=64; 256 blocks)
  gemm_t<128, 64, 64, 2, u16, u16, float><<<dim3(DIN / 64, ML / 128), 256, 0, stream>>>(
      brb, W_ff1, b_ff1, bffh, ML, DIN, DD);
  // 9. ff2 + bias -> mb  (BK=64; 256 blocks)
  gemm_t<64, 64, 64, 1, float, u16, float><<<dim3(DD / 64, ML / 64), 256, 0, stream>>>(
      bffh, W_ff2, b_ff2, mb, ML, DD, DIN);
  // 10. final
  final_kernel<<<ML, 256, 0, stream>>>(rb, mb, x, g2, b2, out);
}